// Round 3
// baseline (508.520 us; speedup 1.0000x reference)
//
#include <hip/hip_runtime.h>
#include <hip/hip_bf16.h>
#include <cstdint>
#include <cstddef>

// ---------------- types ----------------
typedef float f32x4v __attribute__((ext_vector_type(4)));
typedef __bf16 bf16x8 __attribute__((ext_vector_type(8)));
typedef unsigned short u16x4 __attribute__((ext_vector_type(4)));

#define GAS1(p) ((__attribute__((address_space(1))) void*)(p))
#define LAS3(p) ((__attribute__((address_space(3))) void*)(p))

// B=4, S=4096, D=H=1024. M = B*S = 16384. GEMM N = 2*H = 2048 (k | th stacked).
// KTH layout: [M][2048] fp32, cols 0..1023 = k (z-gate), 1024..2047 = th (candidate).

// ---------------- fp32 -> bf16 conversion ----------------
__global__ void cvt_f32_bf16(const float* __restrict__ src,
                             unsigned short* __restrict__ dst, int n4) {
  int i = blockIdx.x * blockDim.x + threadIdx.x;
  if (i >= n4) return;
  float4 v = reinterpret_cast<const float4*>(src)[i];
  u16x4 o;
  o[0] = __builtin_bit_cast(unsigned short, (__bf16)v.x);
  o[1] = __builtin_bit_cast(unsigned short, (__bf16)v.y);
  o[2] = __builtin_bit_cast(unsigned short, (__bf16)v.z);
  o[3] = __builtin_bit_cast(unsigned short, (__bf16)v.w);
  reinterpret_cast<u16x4*>(dst)[i] = o;
}

// ---------------- bf16 MFMA GEMM, C = A * W^T + bias (m97 structure) ----------------
// A: [M][1024] bf16 row-major. W: [2048][1024] bf16 row-major (B^T input).
// C: [M][2048] fp32. 128x128 tile, 4 waves (2x2 quadrants of 64x64), BK=32.
__global__ __launch_bounds__(256) void gemm_bt(
    const __bf16* __restrict__ A, const __bf16* __restrict__ Bw,
    const float* __restrict__ bz, const float* __restrict__ bh,
    float* __restrict__ C) {
  __shared__ __bf16 Als[128 * 32];
  __shared__ __bf16 Bls[128 * 32];
  const int tid = threadIdx.x;
  const int w = tid >> 6, l = tid & 63;
  const int bm = blockIdx.x, bn = blockIdx.y;
  const int wr = w >> 1, wc = w & 1;

  f32x4v acc[4][4] = {};

  // staging: thread i loads 16B; LDS dest is linear in thread id (gload_lds constraint)
  const int r0 = tid >> 2;            // row within 64-row group
  const int c0 = (tid & 3) * 8;       // k-elem offset
  const __bf16* ga0 = A + (size_t)(bm * 128 + r0) * 1024 + c0;
  const __bf16* ga1 = ga0 + (size_t)64 * 1024;
  const __bf16* gb0 = Bw + (size_t)(bn * 128 + r0) * 1024 + c0;
  const __bf16* gb1 = gb0 + (size_t)64 * 1024;
  __bf16* lsA0 = Als + w * 512;          // wave-uniform bases; HW adds lane*16B
  __bf16* lsA1 = Als + 2048 + w * 512;
  __bf16* lsB0 = Bls + w * 512;
  __bf16* lsB1 = Bls + 2048 + w * 512;

  const int lr = l & 15, lk = (l >> 4) * 8;

  for (int kt = 0; kt < 32; ++kt) {
    const int ko = kt * 32;
    __builtin_amdgcn_global_load_lds(GAS1(ga0 + ko), LAS3(lsA0), 16, 0, 0);
    __builtin_amdgcn_global_load_lds(GAS1(ga1 + ko), LAS3(lsA1), 16, 0, 0);
    __builtin_amdgcn_global_load_lds(GAS1(gb0 + ko), LAS3(lsB0), 16, 0, 0);
    __builtin_amdgcn_global_load_lds(GAS1(gb1 + ko), LAS3(lsB1), 16, 0, 0);
    asm volatile("s_waitcnt vmcnt(0)" ::: "memory");
    __syncthreads();

    bf16x8 af[4], bv[4];
#pragma unroll
    for (int f = 0; f < 4; ++f) {
      af[f] = *reinterpret_cast<const bf16x8*>(Als + (wr * 64 + f * 16 + lr) * 32 + lk);
      bv[f] = *reinterpret_cast<const bf16x8*>(Bls + (wc * 64 + f * 16 + lr) * 32 + lk);
    }
#pragma unroll
    for (int m = 0; m < 4; ++m)
#pragma unroll
      for (int n = 0; n < 4; ++n)
        acc[m][n] = __builtin_amdgcn_mfma_f32_16x16x32_bf16(af[m], bv[n], acc[m][n], 0, 0, 0);
    __syncthreads();
  }

  // C/D layout (m89-verified): col = lane&15, row = (lane>>4)*4 + reg
  const int lg = l >> 4;
#pragma unroll
  for (int m = 0; m < 4; ++m) {
    const int row = bm * 128 + wr * 64 + m * 16 + lg * 4;
#pragma unroll
    for (int n = 0; n < 4; ++n) {
      const int col = bn * 128 + wc * 64 + n * 16 + lr;
      const float bias = (col < 1024) ? bz[col] : bh[col - 1024];
#pragma unroll
      for (int r = 0; r < 4; ++r)
        C[(size_t)(row + r) * 2048 + col] = acc[m][n][r] + bias;
    }
  }
}

// ---------------- scan helpers ----------------
// a = 1 - sigmoid(k) (the carry coeff), bq = sigmoid(k) * g(th)
__device__ __forceinline__ void gru_step(float k, float t, float& a, float& bq) {
  float ek = __expf(k);
  a = 1.0f / (1.0f + ek);            // 1 - z
  float z = 1.0f - a;                // sigmoid(k)
  float g = (t >= 0.0f) ? (t + 0.5f) : (1.0f / (1.0f + __expf(-t)));
  bq = z * g;
}

// NC=64 chunks of CL=64 steps. 1024 channel-groups (float4 over H), 4096 channels.
// thread id -> q = channel-group (b*256+hq), c = chunk.

// Pass 1: per-chunk summary (A = prod a, L = local scan with h_in = 0)
__global__ void pass1_summary(const float* __restrict__ KTH, float* __restrict__ SA,
                              float* __restrict__ SB) {
  int tid = blockIdx.x * 256 + threadIdx.x;   // 65536 threads
  int q = tid & 1023, c = tid >> 10;
  int b = q >> 8, hq = q & 255;
  const float4* kp = reinterpret_cast<const float4*>(KTH) + ((size_t)(b * 4096 + c * 64)) * 512 + hq;
  float4 A = make_float4(1.f, 1.f, 1.f, 1.f);
  float4 L = make_float4(0.f, 0.f, 0.f, 0.f);
#pragma unroll 4
  for (int i = 0; i < 64; ++i) {
    float4 k4 = kp[0];
    float4 t4 = kp[256];
    kp += 512;
    float a, bq;
    gru_step(k4.x, t4.x, a, bq); A.x *= a; L.x = a * L.x + bq;
    gru_step(k4.y, t4.y, a, bq); A.y *= a; L.y = a * L.y + bq;
    gru_step(k4.z, t4.z, a, bq); A.z *= a; L.z = a * L.z + bq;
    gru_step(k4.w, t4.w, a, bq); A.w *= a; L.w = a * L.w + bq;
  }
  reinterpret_cast<float4*>(SA)[c * 1024 + q] = A;
  reinterpret_cast<float4*>(SB)[c * 1024 + q] = L;
}

// Pass 2: sequential scan over the 64 chunk summaries; emits h entering each chunk
__global__ void pass2_chunkscan(const float* __restrict__ SA, const float* __restrict__ SB,
                                float* __restrict__ Hin) {
  int q = blockIdx.x * 256 + threadIdx.x;     // 1024 threads
  float4 h = make_float4(0.5f, 0.5f, 0.5f, 0.5f);  // h_0 = g(0) = 0.5
  for (int c = 0; c < 64; ++c) {
    reinterpret_cast<float4*>(Hin)[c * 1024 + q] = h;
    float4 A = reinterpret_cast<const float4*>(SA)[c * 1024 + q];
    float4 Bq = reinterpret_cast<const float4*>(SB)[c * 1024 + q];
    h.x = A.x * h.x + Bq.x;
    h.y = A.y * h.y + Bq.y;
    h.z = A.z * h.z + Bq.z;
    h.w = A.w * h.w + Bq.w;
  }
}

// Pass 3: re-walk chunk with correct h_in, emit h. MODE 0: bf16 (layer-1 -> layer-2 input)
// + fp32 h_n row. MODE 1: fp32 h2 to d_out + fp32 h_n row.
template <int MODE>
__global__ void pass3_emit(const float* __restrict__ KTH, const float* __restrict__ Hin,
                           unsigned short* __restrict__ h1b, float* __restrict__ out,
                           float* __restrict__ hn) {
  int tid = blockIdx.x * 256 + threadIdx.x;   // 65536 threads
  int q = tid & 1023, c = tid >> 10;
  int b = q >> 8, hq = q & 255;
  const float4* kp = reinterpret_cast<const float4*>(KTH) + ((size_t)(b * 4096 + c * 64)) * 512 + hq;
  float4 h = reinterpret_cast<const float4*>(Hin)[c * 1024 + q];
#pragma unroll 4
  for (int i = 0; i < 64; ++i) {
    float4 k4 = kp[0];
    float4 t4 = kp[256];
    kp += 512;
    float a, bq;
    gru_step(k4.x, t4.x, a, bq); h.x = a * h.x + bq;
    gru_step(k4.y, t4.y, a, bq); h.y = a * h.y + bq;
    gru_step(k4.z, t4.z, a, bq); h.z = a * h.z + bq;
    gru_step(k4.w, t4.w, a, bq); h.w = a * h.w + bq;
    size_t row = (size_t)(b * 4096 + c * 64 + i);
    if (MODE == 0) {
      u16x4 o;
      o[0] = __builtin_bit_cast(unsigned short, (__bf16)h.x);
      o[1] = __builtin_bit_cast(unsigned short, (__bf16)h.y);
      o[2] = __builtin_bit_cast(unsigned short, (__bf16)h.z);
      o[3] = __builtin_bit_cast(unsigned short, (__bf16)h.w);
      reinterpret_cast<u16x4*>(h1b)[row * 256 + hq] = o;
    } else {
      reinterpret_cast<float4*>(out)[row * 256 + hq] = h;
    }
  }
  if (c == 63) {  // h at s = S-1
    reinterpret_cast<float4*>(hn)[b * 256 + hq] = h;
  }
}

// ---------------- launcher ----------------
extern "C" void kernel_launch(void* const* d_in, const int* in_sizes, int n_in,
                              void* d_out, int out_size, void* d_ws, size_t ws_size,
                              hipStream_t stream) {
  const float* x   = (const float*)d_in[0];
  const float* Wz0 = (const float*)d_in[1];
  const float* bz0 = (const float*)d_in[2];
  const float* Wh0 = (const float*)d_in[3];
  const float* bh0 = (const float*)d_in[4];
  const float* Wz1 = (const float*)d_in[5];
  const float* bz1 = (const float*)d_in[6];
  const float* Wh1 = (const float*)d_in[7];
  const float* bh1 = (const float*)d_in[8];
  float* out = (float*)d_out;

  char* ws = (char*)d_ws;
  float*  KTH = (float*)(ws);                          // 16384*2048*4 = 128 MB
  __bf16* XB  = (__bf16*)(ws + 134217728);             // 16384*1024*2 = 32 MB (x_bf16, then h1_bf16)
  __bf16* WC0 = (__bf16*)(ws + 167772160);             // 2048*1024*2 = 4 MB
  __bf16* WC1 = (__bf16*)(ws + 171966464);             // 4 MB
  float*  SA  = (float*)(ws + 176160768);              // 64*4096*4 = 1 MB
  float*  SB  = (float*)(ws + 177209344);              // 1 MB
  float*  Hin = (float*)(ws + 178257920);              // 1 MB

  float* hn0 = out + 16777216;          // h_n[0] = h1[:, -1, :]
  float* hn1 = out + 16777216 + 4096;   // h_n[1] = h2[:, -1, :]

  // conversions to bf16
  cvt_f32_bf16<<<16384, 256, 0, stream>>>(x, (unsigned short*)XB, 4194304);
  cvt_f32_bf16<<<1024, 256, 0, stream>>>(Wz0, (unsigned short*)WC0, 262144);
  cvt_f32_bf16<<<1024, 256, 0, stream>>>(Wh0, (unsigned short*)WC0 + 1048576, 262144);
  cvt_f32_bf16<<<1024, 256, 0, stream>>>(Wz1, (unsigned short*)WC1, 262144);
  cvt_f32_bf16<<<1024, 256, 0, stream>>>(Wh1, (unsigned short*)WC1 + 1048576, 262144);

  // ---- layer 1 ----
  gemm_bt<<<dim3(128, 16), 256, 0, stream>>>(XB, WC0, bz0, bh0, KTH);
  pass1_summary<<<256, 256, 0, stream>>>(KTH, SA, SB);
  pass2_chunkscan<<<4, 256, 0, stream>>>(SA, SB, Hin);
  pass3_emit<0><<<256, 256, 0, stream>>>(KTH, Hin, (unsigned short*)XB, nullptr, hn0);

  // ---- layer 2 ----
  gemm_bt<<<dim3(128, 16), 256, 0, stream>>>(XB, WC1, bz1, bh1, KTH);
  pass1_summary<<<256, 256, 0, stream>>>(KTH, SA, SB);
  pass2_chunkscan<<<4, 256, 0, stream>>>(SA, SB, Hin);
  pass3_emit<1><<<256, 256, 0, stream>>>(KTH, Hin, nullptr, out, hn1);
}